// Round 8
// baseline (242.331 us; speedup 1.0000x reference)
//
#include <hip/hip_runtime.h>

#define N_NODES_C 100000
#define N_EDGES_C 1200000
#define NQUADS_C 300000
#define NUM_GRAPHS_C 64
#define D_C 64
#define BN_EPS_C 1e-5f

#define BU_SH 7                 // 128 nodes per bucket
#define NB_C 782                // ceil(100000/128)
#define PART_B 512              // partition blocks
#define QPB 586                 // ceil(300000/512) quads per partition block
#define NSTRIP_C 6250           // 100000/16

typedef unsigned short u16;
typedef unsigned int u32;

using frag_ab = __attribute__((ext_vector_type(8))) short;  // 8 bf16 (4 VGPRs)
using f32x4   = __attribute__((ext_vector_type(4))) float;

__device__ __forceinline__ u16 f2bf(float f) {  // RTNE
    u32 x = __float_as_uint(f);
    x += 0x7fffu + ((x >> 16) & 1u);
    return (u16)(x >> 16);
}
__device__ __forceinline__ float blo(u32 u) { return __uint_as_float(u << 16); }
__device__ __forceinline__ float bhi(u32 u) { return __uint_as_float(u & 0xffff0000u); }

// ============ atomic-free CSR build (radix partition, LDS ranks) ==========

// ---- A: per-block bucket histogram; blocks 0-15 also do W-prep -----------
__global__ void __launch_bounds__(256) k_hist(const int* __restrict__ dst,
                                              u32* __restrict__ hist_all,
                                              const float* __restrict__ W1,
                                              const float* __restrict__ W2,
                                              u16* __restrict__ Wb1,
                                              u16* __restrict__ Wb2,
                                              u16* __restrict__ T,
                                              u16* __restrict__ T2) {
    __shared__ u32 hist[NB_C];
    int b = blockIdx.x, t = threadIdx.x;
    int gi = b * 256 + t;
    if (gi < 4096) {  // W[k][n] -> Wb[n][k]  (merged prepW: saves a launch)
        int n = gi >> 6, k = gi & 63;
        Wb1[gi] = f2bf(W1[k * 64 + n]);
        Wb2[gi] = f2bf(W2[k * 64 + n]);
    }
    if (gi < 64) {
        T[(size_t)N_NODES_C * 64 + gi] = 0;   // zero rows (gather padding)
        T2[(size_t)N_NODES_C * 64 + gi] = 0;
    }
    for (int i = t; i < NB_C; i += 256) hist[i] = 0;
    __syncthreads();
    int qlo = b * QPB, qhi = qlo + QPB; if (qhi > NQUADS_C) qhi = NQUADS_C;
    const int4* d4 = (const int4*)dst;
    for (int i = qlo + t; i < qhi; i += 256) {
        int4 d = d4[i];
        atomicAdd(&hist[d.x >> BU_SH], 1u);
        atomicAdd(&hist[d.y >> BU_SH], 1u);
        atomicAdd(&hist[d.z >> BU_SH], 1u);
        atomicAdd(&hist[d.w >> BU_SH], 1u);
    }
    __syncthreads();
    for (int i = t; i < NB_C; i += 256) hist_all[(size_t)b * NB_C + i] = hist[i];
}

// ---- B: per-bucket exclusive scan along the 512 blocks (wave/bucket) -----
__global__ void __launch_bounds__(256) k_pscan(const u32* __restrict__ hist_all,
                                               u32* __restrict__ partLocal,
                                               u32* __restrict__ bucketTotal) {
    int wv = blockIdx.x * 4 + (threadIdx.x >> 6);
    int l = threadIdx.x & 63;
    if (wv >= NB_C) return;
    u32 v[8];
#pragma unroll
    for (int j = 0; j < 8; ++j) v[j] = hist_all[(size_t)(l * 8 + j) * NB_C + wv];
    u32 s = 0;
#pragma unroll
    for (int j = 0; j < 8; ++j) { u32 tv = v[j]; v[j] = s; s += tv; }
    u32 run = s;  // wave exclusive scan of per-lane sums
#pragma unroll
    for (int off = 1; off < 64; off <<= 1) {
        u32 y = __shfl_up(run, off);
        if (l >= off) run += y;
    }
    u32 excl = run - s;
#pragma unroll
    for (int j = 0; j < 8; ++j)
        partLocal[(size_t)(l * 8 + j) * NB_C + wv] = excl + v[j];
    if (l == 63) bucketTotal[wv] = run;  // inclusive total
}

// ---- C: scan bucket totals -> bucketStart --------------------------------
__global__ void __launch_bounds__(1024) k_bscan(const u32* __restrict__ bucketTotal,
                                                u32* __restrict__ bucketStart) {
    __shared__ u32 sh[1024];
    int t = threadIdx.x;
    u32 c = (t < NB_C) ? bucketTotal[t] : 0;
    u32 val = c;
    sh[t] = val;
    __syncthreads();
#pragma unroll
    for (int off = 1; off < 1024; off <<= 1) {
        u32 y = (t >= off) ? sh[t - off] : 0;
        __syncthreads();
        val += y;
        sh[t] = val;
        __syncthreads();
    }
    if (t < NB_C) bucketStart[t] = val - c;
    if (t == 0) bucketStart[NB_C] = N_EDGES_C;
}

// ---- D: partition scatter — LDS ranks, packed u32, XCD-clustered ---------
__global__ void __launch_bounds__(256) k_part(const int* __restrict__ src,
                                              const int* __restrict__ dst,
                                              const u32* __restrict__ partLocal,
                                              const u32* __restrict__ bucketStart,
                                              u32* __restrict__ pairs) {
    __shared__ u32 baseLDS[NB_C];
    __shared__ u32 rank[NB_C];
    int lb = ((blockIdx.x & 7) << 6) | (blockIdx.x >> 3);  // XCD-contiguous
    int t = threadIdx.x;
    for (int i = t; i < NB_C; i += 256) {
        baseLDS[i] = bucketStart[i] + partLocal[(size_t)lb * NB_C + i];
        rank[i] = 0;
    }
    __syncthreads();
    int qlo = lb * QPB, qhi = qlo + QPB; if (qhi > NQUADS_C) qhi = NQUADS_C;
    const int4* d4 = (const int4*)dst;
    const int4* s4 = (const int4*)src;
    for (int i = qlo + t; i < qhi; i += 256) {
        int4 d = d4[i];
        int4 s = s4[i];
        int dd[4] = {d.x, d.y, d.z, d.w};
        int ss[4] = {s.x, s.y, s.z, s.w};
#pragma unroll
        for (int k = 0; k < 4; ++k) {
            int bu = dd[k] >> BU_SH;
            u32 r = atomicAdd(&rank[bu], 1u);  // LDS atomic
            pairs[baseLDS[bu] + r] = (u32)ss[k] | ((u32)(dd[k] & 127) << 17);
        }
    }
}

// ---- E: per-bucket CSR finalize: cnt, start, col (all LDS-local) ---------
__global__ void __launch_bounds__(256) k_csr(const u32* __restrict__ pairs,
                                             const u32* __restrict__ bucketStart,
                                             int* __restrict__ cnt,
                                             int* __restrict__ start,
                                             int* __restrict__ col) {
    __shared__ u32 cl[128];
    __shared__ u32 sl[128];
    __shared__ u32 rk[128];
    __shared__ int sh[256];
    int bu = blockIdx.x, t = threadIdx.x;
    int n0 = bu << BU_SH;
    u32 seg0 = bucketStart[bu], seg1 = bucketStart[bu + 1];
    if (t < 128) { cl[t] = 0; rk[t] = 0; }
    __syncthreads();
    for (u32 i = seg0 + t; i < seg1; i += 256)
        atomicAdd(&cl[pairs[i] >> 17], 1u);  // LDS atomic
    __syncthreads();
    int c = (t < 128) ? (int)cl[t] : 0;
    int val = c;
    sh[t] = val;
    __syncthreads();
#pragma unroll
    for (int off = 1; off < 128; off <<= 1) {
        int y = (t >= off) ? sh[t - off] : 0;
        __syncthreads();
        val += y;
        sh[t] = val;
        __syncthreads();
    }
    if (t < 128) {
        int node = n0 + t;
        u32 st = seg0 + (u32)(val - c);
        sl[t] = st;
        if (node < N_NODES_C) { cnt[node] = c; start[node] = (int)st; }
    }
    __syncthreads();
    for (u32 i = seg0 + t; i < seg1; i += 256) {
        u32 pr = pairs[i];
        u32 loc = pr >> 17;
        u32 r = atomicAdd(&rk[loc], 1u);  // LDS atomic
        col[sl[loc] + r] = (int)(pr & 0x1ffffu);
    }
}

// ------------------- xw1: fused x->bf16 convert + GEMM1 + dinv ------------
__device__ __forceinline__ frag_ab cvt8(const float* __restrict__ p) {
    float4 f0 = *(const float4*)p;
    float4 f1 = *(const float4*)(p + 4);
    frag_ab r;
    r[0] = (short)f2bf(f0.x); r[1] = (short)f2bf(f0.y);
    r[2] = (short)f2bf(f0.z); r[3] = (short)f2bf(f0.w);
    r[4] = (short)f2bf(f1.x); r[5] = (short)f2bf(f1.y);
    r[6] = (short)f2bf(f1.z); r[7] = (short)f2bf(f1.w);
    return r;
}

__global__ void __launch_bounds__(256) k_xw1(
        const float* __restrict__ x, const u16* __restrict__ Wb,
        const int* __restrict__ cnt, u16* __restrict__ T) {
    int lane = threadIdx.x & 63;
    int q = lane >> 4, ln = lane & 15;
    int wave = blockIdx.x * 4 + (threadIdx.x >> 6);
    if (wave >= NSTRIP_C) return;
    frag_ab bfr[4][2];
#pragma unroll
    for (int nt = 0; nt < 4; ++nt)
#pragma unroll
        for (int kh = 0; kh < 2; ++kh)
            bfr[nt][kh] = *(const frag_ab*)(Wb + (nt * 16 + ln) * 64 + kh * 32 + q * 8);
    int r0 = wave * 16;
    const float* xr = x + (size_t)(r0 + ln) * 64;
    frag_ab a0 = cvt8(xr + q * 8);
    frag_ab a1 = cvt8(xr + 32 + q * 8);
    f32x4 acc[4];
#pragma unroll
    for (int nt = 0; nt < 4; ++nt) {
        acc[nt] = (f32x4){0.f, 0.f, 0.f, 0.f};
        acc[nt] = __builtin_amdgcn_mfma_f32_16x16x32_bf16(a0, bfr[nt][0], acc[nt], 0, 0, 0);
        acc[nt] = __builtin_amdgcn_mfma_f32_16x16x32_bf16(a1, bfr[nt][1], acc[nt], 0, 0, 0);
    }
    float di[4];
#pragma unroll
    for (int reg = 0; reg < 4; ++reg)
        di[reg] = rsqrtf((float)(cnt[r0 + q * 4 + reg] + 1));
#pragma unroll
    for (int nt = 0; nt < 4; ++nt)
#pragma unroll
        for (int reg = 0; reg < 4; ++reg)
            T[(size_t)(r0 + q * 4 + reg) * 64 + nt * 16 + ln] =
                f2bf(acc[nt][reg] * di[reg]);
}

// ---- gather core: 8 rows / load iteration (uint4 per lane) ---------------
// lane (h=lane>>3, c=lane&7): lane loads 16 B (8 bf16 cols c*8..c*8+7) of
// row-slot 8j+h; wave covers 8 rows (1 KB) per load instr, 2 KB in flight
// when 2-unrolled (2x the 4-row scheme's depth, half the load+shfl issue).
// Padded slots hit the hot zero row (L1-resident). After the loop: 24
// shfl_xor reduce -> all lanes hold all 8 col-group totals.
#define GATHER_NODE(OUT0,OUT1,OUT2,OUT3,OUT4,OUT5,OUT6,OUT7)               \
    float OUT0 = 0.f, OUT1 = 0.f, OUT2 = 0.f, OUT3 = 0.f;                  \
    float OUT4 = 0.f, OUT5 = 0.f, OUT6 = 0.f, OUT7 = 0.f;                  \
    {                                                                      \
        int iters = (deg + 8) >> 3;                                        \
        int sl = h;                                                        \
        int j = 0;                                                         \
        for (; j + 2 <= iters; j += 2) {                                   \
            int i0 = __shfl(cv, sl);                                       \
            int i1 = __shfl(cv, sl + 8);                                   \
            uint4 t0 = *(const uint4*)(T + (((size_t)(u32)i0) << 6) + (c << 3)); \
            uint4 t1 = *(const uint4*)(T + (((size_t)(u32)i1) << 6) + (c << 3)); \
            OUT0 += blo(t0.x); OUT1 += bhi(t0.x); OUT2 += blo(t0.y); OUT3 += bhi(t0.y); \
            OUT4 += blo(t0.z); OUT5 += bhi(t0.z); OUT6 += blo(t0.w); OUT7 += bhi(t0.w); \
            OUT0 += blo(t1.x); OUT1 += bhi(t1.x); OUT2 += blo(t1.y); OUT3 += bhi(t1.y); \
            OUT4 += blo(t1.z); OUT5 += bhi(t1.z); OUT6 += blo(t1.w); OUT7 += bhi(t1.w); \
            sl += 16;                                                      \
        }                                                                  \
        if (j < iters) {                                                   \
            int i0 = __shfl(cv, sl);                                       \
            uint4 t0 = *(const uint4*)(T + (((size_t)(u32)i0) << 6) + (c << 3)); \
            OUT0 += blo(t0.x); OUT1 += bhi(t0.x); OUT2 += blo(t0.y); OUT3 += bhi(t0.y); \
            OUT4 += blo(t0.z); OUT5 += bhi(t0.z); OUT6 += blo(t0.w); OUT7 += bhi(t0.w); \
        }                                                                  \
    }                                                                      \
    OUT0 += __shfl_xor(OUT0, 8); OUT0 += __shfl_xor(OUT0, 16); OUT0 += __shfl_xor(OUT0, 32); \
    OUT1 += __shfl_xor(OUT1, 8); OUT1 += __shfl_xor(OUT1, 16); OUT1 += __shfl_xor(OUT1, 32); \
    OUT2 += __shfl_xor(OUT2, 8); OUT2 += __shfl_xor(OUT2, 16); OUT2 += __shfl_xor(OUT2, 32); \
    OUT3 += __shfl_xor(OUT3, 8); OUT3 += __shfl_xor(OUT3, 16); OUT3 += __shfl_xor(OUT3, 32); \
    OUT4 += __shfl_xor(OUT4, 8); OUT4 += __shfl_xor(OUT4, 16); OUT4 += __shfl_xor(OUT4, 32); \
    OUT5 += __shfl_xor(OUT5, 8); OUT5 += __shfl_xor(OUT5, 16); OUT5 += __shfl_xor(OUT5, 32); \
    OUT6 += __shfl_xor(OUT6, 8); OUT6 += __shfl_xor(OUT6, 16); OUT6 += __shfl_xor(OUT6, 32); \
    OUT7 += __shfl_xor(OUT7, 8); OUT7 += __shfl_xor(OUT7, 16); OUT7 += __shfl_xor(OUT7, 32);

// ------------------- g1w2: fused gather1 + BN/ReLU + GEMM2 + dinv ---------
__global__ void __launch_bounds__(256) k_g1w2(
        const u16* __restrict__ T, const int* __restrict__ col,
        const int* __restrict__ cnt, const int* __restrict__ start,
        const u16* __restrict__ Wb2,
        const float* __restrict__ b, const float* __restrict__ g,
        const float* __restrict__ be, const float* __restrict__ m,
        const float* __restrict__ v, u16* __restrict__ T2) {
    __shared__ u16 abuf[4][16][64];
    __shared__ float dibuf[4][16];
    const int ZROW = N_NODES_C;
    int lane = threadIdx.x & 63;
    int widx = threadIdx.x >> 6;
    int h = lane >> 3, c = lane & 7;
    int cbase = c << 3;
    float scv[8], c0v[8];
#pragma unroll
    for (int i = 0; i < 8; ++i) {
        float sci = g[cbase + i] * rsqrtf(v[cbase + i] + BN_EPS_C);
        scv[i] = sci;
        c0v[i] = (b[cbase + i] - m[cbase + i]) * sci + be[cbase + i];
    }
    int wave = blockIdx.x * 4 + widx;
    if (wave >= NSTRIP_C) return;
    int r0 = wave * 16;
    char* ab = (char*)&abuf[widx][0][0];

    // pipeline prologue: meta for r0, r0+1; col vector for r0
    int d0 = cnt[r0];
    int s0 = start[r0];
    int d1 = cnt[r0 + 1], s1 = start[r0 + 1];
    int cv0 = col[(size_t)(u32)s0 + lane];

    for (int i = 0; i < 16; ++i) {
        int p = r0 + i;
        int deg = __builtin_amdgcn_readfirstlane(d0);
        int cvR = cv0;
        if (i + 1 < 16) {  // rotate pipeline
            cv0 = col[(size_t)(u32)s1 + lane];
            d0 = d1;
            if (i + 2 < 16) { d1 = cnt[p + 2]; s1 = start[p + 2]; }
        }
        if (deg > 63) deg = 63;
        int cv = (lane < deg) ? cvR : ((lane == deg) ? p : ZROW);
        GATHER_NODE(a0, a1, a2, a3, a4, a5, a6, a7)
        float dr = rsqrtf((float)(deg + 1));
        if (h == 0) {
            float v0 = fmaxf(fmaf(a0 * dr, scv[0], c0v[0]), 0.f);
            float v1 = fmaxf(fmaf(a1 * dr, scv[1], c0v[1]), 0.f);
            float v2 = fmaxf(fmaf(a2 * dr, scv[2], c0v[2]), 0.f);
            float v3 = fmaxf(fmaf(a3 * dr, scv[3], c0v[3]), 0.f);
            float v4 = fmaxf(fmaf(a4 * dr, scv[4], c0v[4]), 0.f);
            float v5 = fmaxf(fmaf(a5 * dr, scv[5], c0v[5]), 0.f);
            float v6 = fmaxf(fmaf(a6 * dr, scv[6], c0v[6]), 0.f);
            float v7 = fmaxf(fmaf(a7 * dr, scv[7], c0v[7]), 0.f);
            uint4 w;
            w.x = (u32)f2bf(v0) | ((u32)f2bf(v1) << 16);
            w.y = (u32)f2bf(v2) | ((u32)f2bf(v3) << 16);
            w.z = (u32)f2bf(v4) | ((u32)f2bf(v5) << 16);
            w.w = (u32)f2bf(v6) | ((u32)f2bf(v7) << 16);
            int boff = i * 128 + ((c * 16) ^ ((i & 7) << 4));  // swizzled
            *(uint4*)(ab + boff) = w;
            if (c == 0) dibuf[widx][i] = dr;
        }
    }

    // ---- GEMM2 phase: A frags from swizzled LDS, B frags from Wb2 --------
    int q = lane >> 4, ln = lane & 15;
    frag_ab bfr[4][2];
#pragma unroll
    for (int nt = 0; nt < 4; ++nt)
#pragma unroll
        for (int kh = 0; kh < 2; ++kh)
            bfr[nt][kh] = *(const frag_ab*)(Wb2 + (nt * 16 + ln) * 64 + kh * 32 + q * 8);
    int sw = (ln & 7) << 4;
    frag_ab fa0 = *(const frag_ab*)(ab + ln * 128 + ((q * 16) ^ sw));
    frag_ab fa1 = *(const frag_ab*)(ab + ln * 128 + ((64 + q * 16) ^ sw));
    f32x4 acc[4];
#pragma unroll
    for (int nt = 0; nt < 4; ++nt) {
        acc[nt] = (f32x4){0.f, 0.f, 0.f, 0.f};
        acc[nt] = __builtin_amdgcn_mfma_f32_16x16x32_bf16(fa0, bfr[nt][0], acc[nt], 0, 0, 0);
        acc[nt] = __builtin_amdgcn_mfma_f32_16x16x32_bf16(fa1, bfr[nt][1], acc[nt], 0, 0, 0);
    }
    float di[4];
#pragma unroll
    for (int reg = 0; reg < 4; ++reg)
        di[reg] = dibuf[widx][q * 4 + reg];
#pragma unroll
    for (int nt = 0; nt < 4; ++nt)
#pragma unroll
        for (int reg = 0; reg < 4; ++reg)
            T2[(size_t)(r0 + q * 4 + reg) * 64 + nt * 16 + ln] =
                f2bf(acc[nt][reg] * di[reg]);
}

// ------------------- gather2: CSR gather + BN/ReLU + mean-pool ------------
__global__ void __launch_bounds__(256) k_gather2(
        const u16* __restrict__ T, const int* __restrict__ col,
        const int* __restrict__ cnt, const int* __restrict__ start,
        const float* __restrict__ b, const float* __restrict__ g,
        const float* __restrict__ be, const float* __restrict__ m,
        const float* __restrict__ v, const int* __restrict__ batch,
        float* __restrict__ pooled) {
    const int ZROW = N_NODES_C;
    int lane = threadIdx.x & 63;
    int h = lane >> 3, c = lane & 7;
    int colown = (c << 3) | h;   // this lane owns exactly one pooled column
    float sc_own = g[colown] * rsqrtf(v[colown] + BN_EPS_C);
    float c0_own = (b[colown] - m[colown]) * sc_own + be[colown];
    int wave = blockIdx.x * 4 + (threadIdx.x >> 6);
    int nwaves = gridDim.x * 4;
    const int chunk = (N_NODES_C + nwaves - 1) / nwaves;
    int p0 = wave * chunk;
    int p1 = p0 + chunk; if (p1 > N_NODES_C) p1 = N_NODES_C;
    if (p0 >= p1) return;

    float psum = 0.f; int curg = -1;

    int d0 = cnt[p0];
    int s0 = start[p0];
    int d1 = 0, s1 = 0;
    if (p0 + 1 < p1) { d1 = cnt[p0 + 1]; s1 = start[p0 + 1]; }
    int cv0 = col[(size_t)(u32)s0 + lane];

    for (int p = p0; p < p1; ++p) {
        int deg = __builtin_amdgcn_readfirstlane(d0);
        int cvR = cv0;
        if (p + 1 < p1) {
            cv0 = col[(size_t)(u32)s1 + lane];
            d0 = d1;
            if (p + 2 < p1) { d1 = cnt[p + 2]; s1 = start[p + 2]; }
        }
        if (deg > 63) deg = 63;
        int cv = (lane < deg) ? cvR : ((lane == deg) ? p : ZROW);
        GATHER_NODE(a0, a1, a2, a3, a4, a5, a6, a7)
        float dr = rsqrtf((float)(deg + 1));
        float asel = (h < 4) ? ((h < 2) ? (h == 0 ? a0 : a1) : (h == 2 ? a2 : a3))
                             : ((h < 6) ? (h == 4 ? a4 : a5) : (h == 6 ? a6 : a7));
        float vh = fmaxf(fmaf(asel * dr, sc_own, c0_own), 0.f);
        int gg = batch[p];
        if (gg != curg) {
            if (curg >= 0) atomicAdd(&pooled[curg * 64 + colown], psum);
            curg = gg; psum = 0.f;
        }
        psum += vh;
    }
    if (curg >= 0) atomicAdd(&pooled[curg * 64 + colown], psum);
}

// ----------------------------- classifier --------------------------------
__global__ void k_final(const float* __restrict__ pooled, const int* __restrict__ batch,
                        const float* __restrict__ Wc, const float* __restrict__ bc,
                        float* __restrict__ out) {
    __shared__ float sp[64 * 65];
    __shared__ int sub[64];
    int t = threadIdx.x;  // 256 threads
    for (int i = t; i < 4096; i += 256) sp[(i >> 6) * 65 + (i & 63)] = pooled[i];
    if (t < 64) {
        int lo = 0, hi = N_NODES_C;
        while (lo < hi) { int mid = (lo + hi) >> 1; if (batch[mid] > t) hi = mid; else lo = mid + 1; }
        sub[t] = lo;  // first index with batch > t
    }
    __syncthreads();
    if (t < 64) {
        int gi = t;
        int lb = gi ? sub[gi - 1] : 0;
        int cntg = sub[gi] - lb;
        float inv = 1.0f / fmaxf((float)cntg, 1.0f);
        float a0 = 0.f, a1 = 0.f;
#pragma unroll 8
        for (int f = 0; f < 64; ++f) {
            float p = sp[gi * 65 + f];
            a0 = fmaf(p, Wc[f * 2 + 0], a0);
            a1 = fmaf(p, Wc[f * 2 + 1], a1);
        }
        out[gi * 2 + 0] = a0 * inv + bc[0];
        out[gi * 2 + 1] = a1 * inv + bc[1];
    }
}

extern "C" void kernel_launch(void* const* d_in, const int* in_sizes, int n_in,
                              void* d_out, int out_size, void* d_ws, size_t ws_size,
                              hipStream_t stream) {
    const float* x    = (const float*)d_in[0];
    const int*   ei   = (const int*)d_in[1];
    const int*   batch= (const int*)d_in[2];
    const float* W1 = (const float*)d_in[3];
    const float* b1 = (const float*)d_in[4];
    const float* g1 = (const float*)d_in[5];
    const float* be1= (const float*)d_in[6];
    const float* m1 = (const float*)d_in[7];
    const float* v1 = (const float*)d_in[8];
    const float* W2 = (const float*)d_in[9];
    const float* b2 = (const float*)d_in[10];
    const float* g2 = (const float*)d_in[11];
    const float* be2= (const float*)d_in[12];
    const float* m2 = (const float*)d_in[13];
    const float* v2 = (const float*)d_in[14];
    const float* Wc = (const float*)d_in[15];
    const float* bc = (const float*)d_in[16];
    float* out = (float*)d_out;

    char* ws = (char*)d_ws;
    size_t off = 0;
    auto alloc = [&](size_t bytes) {
        size_t o = off;
        off = (off + bytes + 511) & ~(size_t)511;
        return o;
    };
    size_t o_pool  = alloc((size_t)NUM_GRAPHS_C * D_C * 4);
    size_t zero_bytes = off;  // only pooled zeroed each call
    size_t o_hist  = alloc((size_t)PART_B * NB_C * 4);     // 1.6 MB
    size_t o_ploc  = alloc((size_t)PART_B * NB_C * 4);     // 1.6 MB
    size_t o_btot  = alloc((size_t)NB_C * 4);
    size_t o_bst   = alloc((size_t)(NB_C + 2) * 4);
    size_t o_pairs = alloc((size_t)N_EDGES_C * 4);         // 4.8 MB packed
    size_t o_cnt   = alloc((size_t)N_NODES_C * 4);
    size_t o_start = alloc((size_t)(N_NODES_C + 64) * 4);
    size_t o_col   = alloc((size_t)(N_EDGES_C + 64) * 4);  // CSR 4.8 MB (+pad)
    size_t o_wb1   = alloc(4096 * 2);
    size_t o_wb2   = alloc(4096 * 2);
    size_t o_t     = alloc((size_t)(N_NODES_C + 1) * D_C * 2);  // +1: zero row
    size_t o_t2    = alloc((size_t)(N_NODES_C + 1) * D_C * 2);  // +1: zero row
    (void)ws_size; (void)in_sizes; (void)n_in; (void)out_size;

    float* pooled = (float*)(ws + o_pool);
    u32*   hist   = (u32*)(ws + o_hist);
    u32*   ploc   = (u32*)(ws + o_ploc);
    u32*   btot   = (u32*)(ws + o_btot);
    u32*   bst    = (u32*)(ws + o_bst);
    u32*   pairs  = (u32*)(ws + o_pairs);
    int*   cnt    = (int*)(ws + o_cnt);
    int*   startp = (int*)(ws + o_start);
    int*   col    = (int*)(ws + o_col);
    u16*   Wb1    = (u16*)(ws + o_wb1);
    u16*   Wb2    = (u16*)(ws + o_wb2);
    u16*   T      = (u16*)(ws + o_t);
    u16*   T2     = (u16*)(ws + o_t2);

    const int* srcp = ei;
    const int* dstp = ei + N_EDGES_C;

    hipMemsetAsync(ws, 0, zero_bytes, stream);

    int gblocks = 2048;   // 8192 persistent waves (gather2)
    int mblocks = 1563;   // 6252 waves: one 16-row strip each
    k_hist<<<PART_B, 256, 0, stream>>>(dstp, hist, W1, W2, Wb1, Wb2, T, T2);
    k_pscan<<<(NB_C + 3) / 4, 256, 0, stream>>>(hist, ploc, btot);
    k_bscan<<<1, 1024, 0, stream>>>(btot, bst);
    k_part<<<PART_B, 256, 0, stream>>>(srcp, dstp, ploc, bst, pairs);
    k_csr<<<NB_C, 256, 0, stream>>>(pairs, bst, cnt, startp, col);

    k_xw1<<<mblocks, 256, 0, stream>>>(x, Wb1, cnt, T);
    k_g1w2<<<mblocks, 256, 0, stream>>>(T, col, cnt, startp, Wb2,
                                        b1, g1, be1, m1, v1, T2);
    k_gather2<<<gblocks, 256, 0, stream>>>(T2, col, cnt, startp, b2, g2, be2, m2, v2,
                                           batch, pooled);
    k_final<<<1, 256, 0, stream>>>(pooled, batch, Wc, bc, out);
}

// Round 9
// 215.476 us; speedup vs baseline: 1.1246x; 1.1246x over previous
//
#include <hip/hip_runtime.h>

#define N_NODES_C 100000
#define N_EDGES_C 1200000
#define NQUADS_C 300000
#define NUM_GRAPHS_C 64
#define D_C 64
#define BN_EPS_C 1e-5f

#define BU_SH 7                 // 128 nodes per bucket
#define NB_C 782                // ceil(100000/128)
#define PART_B 512              // partition blocks
#define QPB 586                 // ceil(300000/512) quads per partition block
#define NSTRIP_C 6250           // 100000/16

typedef unsigned short u16;
typedef unsigned int u32;

using frag_ab = __attribute__((ext_vector_type(8))) short;  // 8 bf16 (4 VGPRs)
using f32x4   = __attribute__((ext_vector_type(4))) float;

__device__ __forceinline__ u16 f2bf(float f) {  // RTNE
    u32 x = __float_as_uint(f);
    x += 0x7fffu + ((x >> 16) & 1u);
    return (u16)(x >> 16);
}
__device__ __forceinline__ float blo(u32 u) { return __uint_as_float(u << 16); }
__device__ __forceinline__ float bhi(u32 u) { return __uint_as_float(u & 0xffff0000u); }

// ============ atomic-free CSR build (radix partition, LDS ranks) ==========

// ---- A: per-block bucket histogram; low blocks also do W-prep ------------
__global__ void __launch_bounds__(256) k_hist(const int* __restrict__ dst,
                                              u32* __restrict__ hist_all,
                                              const float* __restrict__ W1,
                                              const float* __restrict__ W2,
                                              u16* __restrict__ Wb1,
                                              u16* __restrict__ Wb2,
                                              u16* __restrict__ T,
                                              u16* __restrict__ T2) {
    __shared__ u32 hist[NB_C];
    int b = blockIdx.x, t = threadIdx.x;
    int gi = b * 256 + t;
    if (gi < 4096) {  // W[k][n] -> Wb[n][k]  (merged prepW: saves a launch)
        int n = gi >> 6, k = gi & 63;
        Wb1[gi] = f2bf(W1[k * 64 + n]);
        Wb2[gi] = f2bf(W2[k * 64 + n]);
    }
    if (gi < 64) {
        T[(size_t)N_NODES_C * 64 + gi] = 0;   // zero rows (gather padding)
        T2[(size_t)N_NODES_C * 64 + gi] = 0;
    }
    for (int i = t; i < NB_C; i += 256) hist[i] = 0;
    __syncthreads();
    int qlo = b * QPB, qhi = qlo + QPB; if (qhi > NQUADS_C) qhi = NQUADS_C;
    const int4* d4 = (const int4*)dst;
    for (int i = qlo + t; i < qhi; i += 256) {
        int4 d = d4[i];
        atomicAdd(&hist[d.x >> BU_SH], 1u);
        atomicAdd(&hist[d.y >> BU_SH], 1u);
        atomicAdd(&hist[d.z >> BU_SH], 1u);
        atomicAdd(&hist[d.w >> BU_SH], 1u);
    }
    __syncthreads();
    for (int i = t; i < NB_C; i += 256) hist_all[(size_t)b * NB_C + i] = hist[i];
}

// ---- B: per-bucket exclusive scan along the 512 blocks (wave/bucket) -----
__global__ void __launch_bounds__(256) k_pscan(const u32* __restrict__ hist_all,
                                               u32* __restrict__ partLocal,
                                               u32* __restrict__ bucketTotal) {
    int wv = blockIdx.x * 4 + (threadIdx.x >> 6);
    int l = threadIdx.x & 63;
    if (wv >= NB_C) return;
    u32 v[8];
#pragma unroll
    for (int j = 0; j < 8; ++j) v[j] = hist_all[(size_t)(l * 8 + j) * NB_C + wv];
    u32 s = 0;
#pragma unroll
    for (int j = 0; j < 8; ++j) { u32 tv = v[j]; v[j] = s; s += tv; }
    u32 run = s;  // wave exclusive scan of per-lane sums
#pragma unroll
    for (int off = 1; off < 64; off <<= 1) {
        u32 y = __shfl_up(run, off);
        if (l >= off) run += y;
    }
    u32 excl = run - s;
#pragma unroll
    for (int j = 0; j < 8; ++j)
        partLocal[(size_t)(l * 8 + j) * NB_C + wv] = excl + v[j];
    if (l == 63) bucketTotal[wv] = run;  // inclusive total
}

// ---- C: scan bucket totals -> bucketStart --------------------------------
__global__ void __launch_bounds__(1024) k_bscan(const u32* __restrict__ bucketTotal,
                                                u32* __restrict__ bucketStart) {
    __shared__ u32 sh[1024];
    int t = threadIdx.x;
    u32 c = (t < NB_C) ? bucketTotal[t] : 0;
    u32 val = c;
    sh[t] = val;
    __syncthreads();
#pragma unroll
    for (int off = 1; off < 1024; off <<= 1) {
        u32 y = (t >= off) ? sh[t - off] : 0;
        __syncthreads();
        val += y;
        sh[t] = val;
        __syncthreads();
    }
    if (t < NB_C) bucketStart[t] = val - c;
    if (t == 0) bucketStart[NB_C] = N_EDGES_C;
}

// ---- D: partition scatter — LDS ranks, packed u32, XCD-clustered ---------
__global__ void __launch_bounds__(256) k_part(const int* __restrict__ src,
                                              const int* __restrict__ dst,
                                              const u32* __restrict__ partLocal,
                                              const u32* __restrict__ bucketStart,
                                              u32* __restrict__ pairs) {
    __shared__ u32 baseLDS[NB_C];
    __shared__ u32 rank[NB_C];
    int lb = ((blockIdx.x & 7) << 6) | (blockIdx.x >> 3);  // XCD-contiguous
    int t = threadIdx.x;
    for (int i = t; i < NB_C; i += 256) {
        baseLDS[i] = bucketStart[i] + partLocal[(size_t)lb * NB_C + i];
        rank[i] = 0;
    }
    __syncthreads();
    int qlo = lb * QPB, qhi = qlo + QPB; if (qhi > NQUADS_C) qhi = NQUADS_C;
    const int4* d4 = (const int4*)dst;
    const int4* s4 = (const int4*)src;
    for (int i = qlo + t; i < qhi; i += 256) {
        int4 d = d4[i];
        int4 s = s4[i];
        int dd[4] = {d.x, d.y, d.z, d.w};
        int ss[4] = {s.x, s.y, s.z, s.w};
#pragma unroll
        for (int k = 0; k < 4; ++k) {
            int bu = dd[k] >> BU_SH;
            u32 r = atomicAdd(&rank[bu], 1u);  // LDS atomic
            pairs[baseLDS[bu] + r] = (u32)ss[k] | ((u32)(dd[k] & 127) << 17);
        }
    }
}

// ---- E: per-bucket CSR finalize: cnt, start, col (all LDS-local) ---------
__global__ void __launch_bounds__(256) k_csr(const u32* __restrict__ pairs,
                                             const u32* __restrict__ bucketStart,
                                             int* __restrict__ cnt,
                                             int* __restrict__ start,
                                             int* __restrict__ col) {
    __shared__ u32 cl[128];
    __shared__ u32 sl[128];
    __shared__ u32 rk[128];
    __shared__ int sh[256];
    int bu = blockIdx.x, t = threadIdx.x;
    int n0 = bu << BU_SH;
    u32 seg0 = bucketStart[bu], seg1 = bucketStart[bu + 1];
    if (t < 128) { cl[t] = 0; rk[t] = 0; }
    __syncthreads();
    for (u32 i = seg0 + t; i < seg1; i += 256)
        atomicAdd(&cl[pairs[i] >> 17], 1u);  // LDS atomic
    __syncthreads();
    int c = (t < 128) ? (int)cl[t] : 0;
    int val = c;
    sh[t] = val;
    __syncthreads();
#pragma unroll
    for (int off = 1; off < 128; off <<= 1) {
        int y = (t >= off) ? sh[t - off] : 0;
        __syncthreads();
        val += y;
        sh[t] = val;
        __syncthreads();
    }
    if (t < 128) {
        int node = n0 + t;
        u32 st = seg0 + (u32)(val - c);
        sl[t] = st;
        if (node < N_NODES_C) { cnt[node] = c; start[node] = (int)st; }
    }
    __syncthreads();
    for (u32 i = seg0 + t; i < seg1; i += 256) {
        u32 pr = pairs[i];
        u32 loc = pr >> 17;
        u32 r = atomicAdd(&rk[loc], 1u);  // LDS atomic
        col[sl[loc] + r] = (int)(pr & 0x1ffffu);
    }
}

// ------------------- xw1: fused x->bf16 convert + GEMM1 + dinv ------------
__device__ __forceinline__ frag_ab cvt8(const float* __restrict__ p) {
    float4 f0 = *(const float4*)p;
    float4 f1 = *(const float4*)(p + 4);
    frag_ab r;
    r[0] = (short)f2bf(f0.x); r[1] = (short)f2bf(f0.y);
    r[2] = (short)f2bf(f0.z); r[3] = (short)f2bf(f0.w);
    r[4] = (short)f2bf(f1.x); r[5] = (short)f2bf(f1.y);
    r[6] = (short)f2bf(f1.z); r[7] = (short)f2bf(f1.w);
    return r;
}

__global__ void __launch_bounds__(256) k_xw1(
        const float* __restrict__ x, const u16* __restrict__ Wb,
        const int* __restrict__ cnt, u16* __restrict__ T) {
    int lane = threadIdx.x & 63;
    int q = lane >> 4, ln = lane & 15;
    int wave = blockIdx.x * 4 + (threadIdx.x >> 6);
    if (wave >= NSTRIP_C) return;
    frag_ab bfr[4][2];
#pragma unroll
    for (int nt = 0; nt < 4; ++nt)
#pragma unroll
        for (int kh = 0; kh < 2; ++kh)
            bfr[nt][kh] = *(const frag_ab*)(Wb + (nt * 16 + ln) * 64 + kh * 32 + q * 8);
    int r0 = wave * 16;
    const float* xr = x + (size_t)(r0 + ln) * 64;
    frag_ab a0 = cvt8(xr + q * 8);
    frag_ab a1 = cvt8(xr + 32 + q * 8);
    f32x4 acc[4];
#pragma unroll
    for (int nt = 0; nt < 4; ++nt) {
        acc[nt] = (f32x4){0.f, 0.f, 0.f, 0.f};
        acc[nt] = __builtin_amdgcn_mfma_f32_16x16x32_bf16(a0, bfr[nt][0], acc[nt], 0, 0, 0);
        acc[nt] = __builtin_amdgcn_mfma_f32_16x16x32_bf16(a1, bfr[nt][1], acc[nt], 0, 0, 0);
    }
    float di[4];
#pragma unroll
    for (int reg = 0; reg < 4; ++reg)
        di[reg] = rsqrtf((float)(cnt[r0 + q * 4 + reg] + 1));
#pragma unroll
    for (int nt = 0; nt < 4; ++nt)
#pragma unroll
        for (int reg = 0; reg < 4; ++reg)
            T[(size_t)(r0 + q * 4 + reg) * 64 + nt * 16 + ln] =
                f2bf(acc[nt][reg] * di[reg]);
}

// ------------------- g1w2: fused gather1 + BN/ReLU + GEMM2 + dinv ---------
// 4-row gather core (lane h=lane>>4 picks row-slot, c=lane&15 picks 4 bf16
// cols via uint2): the proven 217 us configuration. 8-row variant (R8)
// regressed — gathers are LLC random-row service bound (~1.45 TB/s L2-fill
// plateau across 3 implementations), wider per-lane loads don't help.
__global__ void __launch_bounds__(256) k_g1w2(
        const u16* __restrict__ T, const int* __restrict__ col,
        const int* __restrict__ cnt, const int* __restrict__ start,
        const u16* __restrict__ Wb2,
        const float* __restrict__ b, const float* __restrict__ g,
        const float* __restrict__ be, const float* __restrict__ m,
        const float* __restrict__ v, u16* __restrict__ T2) {
    __shared__ u16 abuf[4][16][64];
    __shared__ float dibuf[4][16];
    const int ZROW = N_NODES_C;
    int lane = threadIdx.x & 63;
    int widx = threadIdx.x >> 6;
    int h = lane >> 4, c = lane & 15;   // h==q, c==ln for the MFMA phase
    int cbase = c << 2;
    float scv[4], c0v[4];
#pragma unroll
    for (int i = 0; i < 4; ++i) {
        float sci = g[cbase + i] * rsqrtf(v[cbase + i] + BN_EPS_C);
        scv[i] = sci;
        c0v[i] = (b[cbase + i] - m[cbase + i]) * sci + be[cbase + i];
    }
    int wave = blockIdx.x * 4 + widx;
    if (wave >= NSTRIP_C) return;
    int r0 = wave * 16;
    char* ab = (char*)&abuf[widx][0][0];

    // pipeline prologue: meta for r0, r0+1; col vector for r0
    int d0 = cnt[r0];
    int s0 = start[r0];
    int d1 = cnt[r0 + 1], s1 = start[r0 + 1];
    int cv0 = col[(size_t)(u32)s0 + lane];

    for (int i = 0; i < 16; ++i) {
        int p = r0 + i;
        int deg = __builtin_amdgcn_readfirstlane(d0);
        int cvR = cv0;
        if (i + 1 < 16) {  // rotate pipeline
            cv0 = col[(size_t)(u32)s1 + lane];
            d0 = d1;
            if (i + 2 < 16) { d1 = cnt[p + 2]; s1 = start[p + 2]; }
        }
        if (deg > 63) deg = 63;
        int cv = (lane < deg) ? cvR : ((lane == deg) ? p : ZROW);
        int iters = (deg + 4) >> 2;  // ceil((deg+1)/4), slots incl. self
        float a0 = 0.f, a1 = 0.f, a2 = 0.f, a3 = 0.f;
        int sl = h;
        int j = 0;
        for (; j + 2 <= iters; j += 2) {
            int i0 = __shfl(cv, sl);
            int i1 = __shfl(cv, sl + 4);
            uint2 t0 = *(const uint2*)(T + (((size_t)(u32)i0) << 6) + (c << 2));
            uint2 t1 = *(const uint2*)(T + (((size_t)(u32)i1) << 6) + (c << 2));
            a0 += blo(t0.x); a1 += bhi(t0.x); a2 += blo(t0.y); a3 += bhi(t0.y);
            a0 += blo(t1.x); a1 += bhi(t1.x); a2 += blo(t1.y); a3 += bhi(t1.y);
            sl += 8;
        }
        if (j < iters) {
            int i0 = __shfl(cv, sl);
            uint2 t0 = *(const uint2*)(T + (((size_t)(u32)i0) << 6) + (c << 2));
            a0 += blo(t0.x); a1 += bhi(t0.x); a2 += blo(t0.y); a3 += bhi(t0.y);
        }
        // reduce across the 4 h-groups
        a0 += __shfl_xor(a0, 16); a0 += __shfl_xor(a0, 32);
        a1 += __shfl_xor(a1, 16); a1 += __shfl_xor(a1, 32);
        a2 += __shfl_xor(a2, 16); a2 += __shfl_xor(a2, 32);
        a3 += __shfl_xor(a3, 16); a3 += __shfl_xor(a3, 32);
        float dr = rsqrtf((float)(deg + 1));
        float v0 = fmaxf(fmaf(a0 * dr, scv[0], c0v[0]), 0.f);
        float v1 = fmaxf(fmaf(a1 * dr, scv[1], c0v[1]), 0.f);
        float v2 = fmaxf(fmaf(a2 * dr, scv[2], c0v[2]), 0.f);
        float v3 = fmaxf(fmaf(a3 * dr, scv[3], c0v[3]), 0.f);
        if (h == 0) {
            u32 w0 = (u32)f2bf(v0) | ((u32)f2bf(v1) << 16);
            u32 w1 = (u32)f2bf(v2) | ((u32)f2bf(v3) << 16);
            int boff = i * 128 + ((c * 8) ^ ((i & 7) << 4));  // swizzled
            *(uint2*)(ab + boff) = make_uint2(w0, w1);
            if (c == 0) dibuf[widx][i] = dr;
        }
    }

    // ---- GEMM2 phase: A frags from swizzled LDS, B frags from Wb2 --------
    int q = h, ln = c;
    frag_ab bfr[4][2];
#pragma unroll
    for (int nt = 0; nt < 4; ++nt)
#pragma unroll
        for (int kh = 0; kh < 2; ++kh)
            bfr[nt][kh] = *(const frag_ab*)(Wb2 + (nt * 16 + ln) * 64 + kh * 32 + q * 8);
    int sw = (ln & 7) << 4;
    frag_ab fa0 = *(const frag_ab*)(ab + ln * 128 + ((q * 16) ^ sw));
    frag_ab fa1 = *(const frag_ab*)(ab + ln * 128 + ((64 + q * 16) ^ sw));
    f32x4 acc[4];
#pragma unroll
    for (int nt = 0; nt < 4; ++nt) {
        acc[nt] = (f32x4){0.f, 0.f, 0.f, 0.f};
        acc[nt] = __builtin_amdgcn_mfma_f32_16x16x32_bf16(fa0, bfr[nt][0], acc[nt], 0, 0, 0);
        acc[nt] = __builtin_amdgcn_mfma_f32_16x16x32_bf16(fa1, bfr[nt][1], acc[nt], 0, 0, 0);
    }
    float di[4];
#pragma unroll
    for (int reg = 0; reg < 4; ++reg)
        di[reg] = dibuf[widx][q * 4 + reg];
#pragma unroll
    for (int nt = 0; nt < 4; ++nt)
#pragma unroll
        for (int reg = 0; reg < 4; ++reg)
            T2[(size_t)(r0 + q * 4 + reg) * 64 + nt * 16 + ln] =
                f2bf(acc[nt][reg] * di[reg]);
}

// ------------------- gather2: CSR gather + BN/ReLU + mean-pool ------------
__global__ void __launch_bounds__(256) k_gather2(
        const u16* __restrict__ T, const int* __restrict__ col,
        const int* __restrict__ cnt, const int* __restrict__ start,
        const float* __restrict__ b, const float* __restrict__ g,
        const float* __restrict__ be, const float* __restrict__ m,
        const float* __restrict__ v, const int* __restrict__ batch,
        float* __restrict__ pooled) {
    const int ZROW = N_NODES_C;
    int lane = threadIdx.x & 63;
    int h = lane >> 4, c = lane & 15;
    int cbase = c << 2;
    int wave = blockIdx.x * 4 + (threadIdx.x >> 6);
    int nwaves = gridDim.x * 4;
    float scv[4], c0v[4];
#pragma unroll
    for (int i = 0; i < 4; ++i) {
        float sci = g[cbase + i] * rsqrtf(v[cbase + i] + BN_EPS_C);
        scv[i] = sci;
        c0v[i] = (b[cbase + i] - m[cbase + i]) * sci + be[cbase + i];
    }
    const int chunk = (N_NODES_C + nwaves - 1) / nwaves;
    int p0 = wave * chunk;
    int p1 = p0 + chunk; if (p1 > N_NODES_C) p1 = N_NODES_C;
    if (p0 >= p1) return;

    float psum = 0.f; int curg = -1;

    int d0 = cnt[p0];
    int s0 = start[p0];
    int d1 = 0, s1 = 0;
    if (p0 + 1 < p1) { d1 = cnt[p0 + 1]; s1 = start[p0 + 1]; }
    int cv0 = col[(size_t)(u32)s0 + lane];

    for (int p = p0; p < p1; ++p) {
        int deg = __builtin_amdgcn_readfirstlane(d0);
        int cvR = cv0;
        if (p + 1 < p1) {
            cv0 = col[(size_t)(u32)s1 + lane];
            d0 = d1;
            if (p + 2 < p1) { d1 = cnt[p + 2]; s1 = start[p + 2]; }
        }
        if (deg > 63) deg = 63;
        int cv = (lane < deg) ? cvR : ((lane == deg) ? p : ZROW);
        int iters = (deg + 4) >> 2;
        float a0 = 0.f, a1 = 0.f, a2 = 0.f, a3 = 0.f;
        int sl = h;
        int j = 0;
        for (; j + 2 <= iters; j += 2) {
            int i0 = __shfl(cv, sl);
            int i1 = __shfl(cv, sl + 4);
            uint2 t0 = *(const uint2*)(T + (((size_t)(u32)i0) << 6) + (c << 2));
            uint2 t1 = *(const uint2*)(T + (((size_t)(u32)i1) << 6) + (c << 2));
            a0 += blo(t0.x); a1 += bhi(t0.x); a2 += blo(t0.y); a3 += bhi(t0.y);
            a0 += blo(t1.x); a1 += bhi(t1.x); a2 += blo(t1.y); a3 += bhi(t1.y);
            sl += 8;
        }
        if (j < iters) {
            int i0 = __shfl(cv, sl);
            uint2 t0 = *(const uint2*)(T + (((size_t)(u32)i0) << 6) + (c << 2));
            a0 += blo(t0.x); a1 += bhi(t0.x); a2 += blo(t0.y); a3 += bhi(t0.y);
        }
        a0 += __shfl_xor(a0, 16); a0 += __shfl_xor(a0, 32);
        a1 += __shfl_xor(a1, 16); a1 += __shfl_xor(a1, 32);
        a2 += __shfl_xor(a2, 16); a2 += __shfl_xor(a2, 32);
        a3 += __shfl_xor(a3, 16); a3 += __shfl_xor(a3, 32);
        float dr = rsqrtf((float)(deg + 1));
        float asel = (h & 2) ? ((h & 1) ? a3 : a2) : ((h & 1) ? a1 : a0);
        float scl  = (h & 2) ? ((h & 1) ? scv[3] : scv[2]) : ((h & 1) ? scv[1] : scv[0]);
        float c0l  = (h & 2) ? ((h & 1) ? c0v[3] : c0v[2]) : ((h & 1) ? c0v[1] : c0v[0]);
        float vh = fmaxf(fmaf(asel * dr, scl, c0l), 0.f);
        int gg = batch[p];
        if (gg != curg) {
            if (curg >= 0) atomicAdd(&pooled[curg * 64 + cbase + h], psum);
            curg = gg; psum = 0.f;
        }
        psum += vh;
    }
    if (curg >= 0) atomicAdd(&pooled[curg * 64 + cbase + h], psum);
}

// ----------------------------- classifier --------------------------------
__global__ void k_final(const float* __restrict__ pooled, const int* __restrict__ batch,
                        const float* __restrict__ Wc, const float* __restrict__ bc,
                        float* __restrict__ out) {
    __shared__ float sp[64 * 65];
    __shared__ int sub[64];
    int t = threadIdx.x;  // 256 threads
    for (int i = t; i < 4096; i += 256) sp[(i >> 6) * 65 + (i & 63)] = pooled[i];
    if (t < 64) {
        int lo = 0, hi = N_NODES_C;
        while (lo < hi) { int mid = (lo + hi) >> 1; if (batch[mid] > t) hi = mid; else lo = mid + 1; }
        sub[t] = lo;  // first index with batch > t
    }
    __syncthreads();
    if (t < 64) {
        int gi = t;
        int lb = gi ? sub[gi - 1] : 0;
        int cntg = sub[gi] - lb;
        float inv = 1.0f / fmaxf((float)cntg, 1.0f);
        float a0 = 0.f, a1 = 0.f;
#pragma unroll 8
        for (int f = 0; f < 64; ++f) {
            float p = sp[gi * 65 + f];
            a0 = fmaf(p, Wc[f * 2 + 0], a0);
            a1 = fmaf(p, Wc[f * 2 + 1], a1);
        }
        out[gi * 2 + 0] = a0 * inv + bc[0];
        out[gi * 2 + 1] = a1 * inv + bc[1];
    }
}

extern "C" void kernel_launch(void* const* d_in, const int* in_sizes, int n_in,
                              void* d_out, int out_size, void* d_ws, size_t ws_size,
                              hipStream_t stream) {
    const float* x    = (const float*)d_in[0];
    const int*   ei   = (const int*)d_in[1];
    const int*   batch= (const int*)d_in[2];
    const float* W1 = (const float*)d_in[3];
    const float* b1 = (const float*)d_in[4];
    const float* g1 = (const float*)d_in[5];
    const float* be1= (const float*)d_in[6];
    const float* m1 = (const float*)d_in[7];
    const float* v1 = (const float*)d_in[8];
    const float* W2 = (const float*)d_in[9];
    const float* b2 = (const float*)d_in[10];
    const float* g2 = (const float*)d_in[11];
    const float* be2= (const float*)d_in[12];
    const float* m2 = (const float*)d_in[13];
    const float* v2 = (const float*)d_in[14];
    const float* Wc = (const float*)d_in[15];
    const float* bc = (const float*)d_in[16];
    float* out = (float*)d_out;

    char* ws = (char*)d_ws;
    size_t off = 0;
    auto alloc = [&](size_t bytes) {
        size_t o = off;
        off = (off + bytes + 511) & ~(size_t)511;
        return o;
    };
    size_t o_pool  = alloc((size_t)NUM_GRAPHS_C * D_C * 4);
    size_t zero_bytes = off;  // only pooled zeroed each call
    size_t o_hist  = alloc((size_t)PART_B * NB_C * 4);     // 1.6 MB
    size_t o_ploc  = alloc((size_t)PART_B * NB_C * 4);     // 1.6 MB
    size_t o_btot  = alloc((size_t)NB_C * 4);
    size_t o_bst   = alloc((size_t)(NB_C + 2) * 4);
    size_t o_pairs = alloc((size_t)N_EDGES_C * 4);         // 4.8 MB packed
    size_t o_cnt   = alloc((size_t)N_NODES_C * 4);
    size_t o_start = alloc((size_t)(N_NODES_C + 64) * 4);
    size_t o_col   = alloc((size_t)(N_EDGES_C + 64) * 4);  // CSR 4.8 MB (+pad)
    size_t o_wb1   = alloc(4096 * 2);
    size_t o_wb2   = alloc(4096 * 2);
    size_t o_t     = alloc((size_t)(N_NODES_C + 1) * D_C * 2);  // +1: zero row
    size_t o_t2    = alloc((size_t)(N_NODES_C + 1) * D_C * 2);  // +1: zero row
    (void)ws_size; (void)in_sizes; (void)n_in; (void)out_size;

    float* pooled = (float*)(ws + o_pool);
    u32*   hist   = (u32*)(ws + o_hist);
    u32*   ploc   = (u32*)(ws + o_ploc);
    u32*   btot   = (u32*)(ws + o_btot);
    u32*   bst    = (u32*)(ws + o_bst);
    u32*   pairs  = (u32*)(ws + o_pairs);
    int*   cnt    = (int*)(ws + o_cnt);
    int*   startp = (int*)(ws + o_start);
    int*   col    = (int*)(ws + o_col);
    u16*   Wb1    = (u16*)(ws + o_wb1);
    u16*   Wb2    = (u16*)(ws + o_wb2);
    u16*   T      = (u16*)(ws + o_t);
    u16*   T2     = (u16*)(ws + o_t2);

    const int* srcp = ei;
    const int* dstp = ei + N_EDGES_C;

    hipMemsetAsync(ws, 0, zero_bytes, stream);

    int gblocks = 2048;   // 8192 persistent waves (gather2)
    int mblocks = 1563;   // 6252 waves: one 16-row strip each
    k_hist<<<PART_B, 256, 0, stream>>>(dstp, hist, W1, W2, Wb1, Wb2, T, T2);
    k_pscan<<<(NB_C + 3) / 4, 256, 0, stream>>>(hist, ploc, btot);
    k_bscan<<<1, 1024, 0, stream>>>(btot, bst);
    k_part<<<PART_B, 256, 0, stream>>>(srcp, dstp, ploc, bst, pairs);
    k_csr<<<NB_C, 256, 0, stream>>>(pairs, bst, cnt, startp, col);

    k_xw1<<<mblocks, 256, 0, stream>>>(x, Wb1, cnt, T);
    k_g1w2<<<mblocks, 256, 0, stream>>>(T, col, cnt, startp, Wb2,
                                        b1, g1, be1, m1, v1, T2);
    k_gather2<<<gblocks, 256, 0, stream>>>(T2, col, cnt, startp, b2, g2, be2, m2, v2,
                                           batch, pooled);
    k_final<<<1, 256, 0, stream>>>(pooled, batch, Wc, bc, out);
}